// Round 20
// baseline (2955.700 us; speedup 1.0000x reference)
//
#include <hip/hip_runtime.h>
#include <cstddef>
#include <cstdint>

// ============================================================================
// DevignModel round 20: gemm_gru8 occupancy fix.
//  - GRU epilogue: 4 quarter-passes, per-wave [64][18] f32 -> LDS 73728->36864 B
//    (4 blocks/CU), write banks 2-way, b128 reads uniform -> ~0 conflicts.
//  - everything else identical to r19.
// ============================================================================

typedef unsigned short u16;
typedef unsigned char u8;
typedef __attribute__((ext_vector_type(8))) short bf16x8;
typedef __attribute__((ext_vector_type(4))) float f32x4;
typedef __attribute__((ext_vector_type(2))) float f32x2;

static __device__ __forceinline__ float bf2f(u16 u) {
  union { unsigned int i; float f; } v; v.i = ((unsigned int)u) << 16; return v.f;
}
static __device__ __forceinline__ u16 f2bf(float f) {
  union { float f; unsigned int i; } v; v.f = f;
  unsigned int r = v.i + 0x7FFFu + ((v.i >> 16) & 1u);
  return (u16)(r >> 16);
}
static __device__ __forceinline__ float sigm(float x) { return 1.f / (1.f + __expf(-x)); }
static __device__ __forceinline__ u8 f2fp8(float x) {
  return (u8)(__builtin_amdgcn_cvt_pk_fp8_f32(x, 0.f, 0, false) & 0xff);
}
static __device__ __forceinline__ float fp82f(u8 b) {
  f32x2 p = __builtin_amdgcn_cvt_pk_f32_fp8((unsigned)b, false);
  return p[0];
}

static __device__ __forceinline__ void gload16(const void* gp, void* lp) {
  __builtin_amdgcn_global_load_lds(
      (const __attribute__((address_space(1))) void*)gp,
      (__attribute__((address_space(3))) void*)lp, 16, 0, 0);
}

__global__ void fail_k(float* out, float code) { out[0] = code; out[1] = code; }

// hb[n][224] bf16 = [feat | 0]  (GRU hold state only)
__global__ void init_hb_k(const float* __restrict__ feat, u16* __restrict__ hb, int N) {
  int total = N * 224;
  for (int i = blockIdx.x * blockDim.x + threadIdx.x; i < total; i += blockDim.x * gridDim.x) {
    int n = i / 224, c = i - n * 224;
    hb[i] = (c < 100) ? f2bf(feat[(size_t)n * 100 + c]) : (u16)0;
  }
}

// dense hq0[n][224] fp8 = [feat | 0]
__global__ void init_hq_k(const float* __restrict__ feat, u8* __restrict__ hq0, int N) {
  int total = N * 224;
  for (int i = blockIdx.x * blockDim.x + threadIdx.x; i < total; i += blockDim.x * gridDim.x) {
    int n = i / 224, c = i - n * 224;
    hq0[i] = (c < 100) ? f2fp8(feat[(size_t)n * 100 + c]) : (u8)0;
  }
}

__global__ void count_deg_k(const int* __restrict__ dst, const int* __restrict__ et,
                            int* __restrict__ deg_et, int N, int E) {
  for (int e = blockIdx.x * blockDim.x + threadIdx.x; e < E; e += blockDim.x * gridDim.x)
    atomicAdd(&deg_et[et[e] * N + dst[e]], 1);
}

// ---- parallel exclusive scan (3 kernels) ----
__global__ __launch_bounds__(1024) void bsum_k(const int* __restrict__ cnt,
                                               int* __restrict__ bsum, int L) {
  __shared__ int buf[1024];
  int i = blockIdx.x * 1024 + threadIdx.x;
  buf[threadIdx.x] = (i < L) ? cnt[i] : 0;
  __syncthreads();
  for (int o = 512; o > 0; o >>= 1) {
    if (threadIdx.x < o) buf[threadIdx.x] += buf[threadIdx.x + o];
    __syncthreads();
  }
  if (threadIdx.x == 0) bsum[blockIdx.x] = buf[0];
}

__global__ __launch_bounds__(1024) void scanb_k(int* __restrict__ bsum, int nb) {
  __shared__ int buf[1024];
  int v = (threadIdx.x < nb) ? bsum[threadIdx.x] : 0;
  buf[threadIdx.x] = v;
  __syncthreads();
  for (int o = 1; o < 1024; o <<= 1) {
    int t = (threadIdx.x >= o) ? buf[threadIdx.x - o] : 0;
    __syncthreads();
    buf[threadIdx.x] += t;
    __syncthreads();
  }
  if (threadIdx.x < nb) bsum[threadIdx.x] = buf[threadIdx.x] - v;
}

__global__ __launch_bounds__(1024) void scan_fin_k(const int* __restrict__ cnt,
                                                   const int* __restrict__ bsum,
                                                   int* __restrict__ off, int L) {
  __shared__ int buf[1024];
  int i = blockIdx.x * 1024 + threadIdx.x;
  int v = (i < L) ? cnt[i] : 0;
  buf[threadIdx.x] = v;
  __syncthreads();
  for (int o = 1; o < 1024; o <<= 1) {
    int t = (threadIdx.x >= o) ? buf[threadIdx.x - o] : 0;
    __syncthreads();
    buf[threadIdx.x] += t;
    __syncthreads();
  }
  if (i < L) off[i] = buf[threadIdx.x] - v + bsum[blockIdx.x];
}

__global__ void copy_int_k(const int* __restrict__ a, int* __restrict__ b, int n) {
  for (int i = blockIdx.x * blockDim.x + threadIdx.x; i < n; i += blockDim.x * gridDim.x) b[i] = a[i];
}

__global__ void fill_src_k(const int* __restrict__ src, const int* __restrict__ dst,
                           const int* __restrict__ et, int* __restrict__ cursor,
                           int* __restrict__ esrc, int N, int E) {
  for (int e = blockIdx.x * blockDim.x + threadIdx.x; e < E; e += blockDim.x * gridDim.x) {
    int p = atomicAdd(&cursor[et[e] * N + dst[e]], 1);
    esrc[p] = src[e];
  }
}

// ---- weight packs (all fp8) ----

__global__ void pack_wcat8_k(const float* __restrict__ W, const float* __restrict__ gb,
                             u8* __restrict__ dst) {
  int total = 200 * 832;
  for (int i = blockIdx.x * blockDim.x + threadIdx.x; i < total; i += blockDim.x * gridDim.x) {
    int o = i / 832, kp = i - o * 832;
    float v = 0.f;
    if (kp < 800) { int k = kp / 200, kk = kp - k * 200; v = W[((size_t)k * 200 + o) * 200 + kk]; }
    else if (kp < 804) v = gb[(kp - 800) * 200 + o];
    dst[i] = f2fp8(v);
  }
}

// Wall8[800][448] fp8, gate-interleaved (row 4o+g)
__global__ void pack_wall8_k(const float* __restrict__ Wih, const float* __restrict__ Whh,
                             u8* __restrict__ dst) {
  int total = 800 * 448;
  for (int i = blockIdx.x * blockDim.x + threadIdx.x; i < total; i += blockDim.x * gridDim.x) {
    int jp = i / 448, kp = i - jp * 448;
    int o = jp >> 2, g = jp & 3;
    float v = 0.f;
    if (g == 0) {
      if (kp < 200) v = Wih[(size_t)o * 200 + kp];
      else if (kp >= 224 && kp < 424) v = Whh[(size_t)o * 200 + (kp - 224)];
    } else if (g == 1) {
      if (kp < 200) v = Wih[(size_t)(200 + o) * 200 + kp];
      else if (kp >= 224 && kp < 424) v = Whh[(size_t)(200 + o) * 200 + (kp - 224)];
    } else if (g == 2) {
      if (kp < 200) v = Wih[(size_t)(400 + o) * 200 + kp];
    } else {
      if (kp >= 224 && kp < 424) v = Whh[(size_t)(400 + o) * 200 + (kp - 224)];
    }
    dst[i] = f2fp8(v);
  }
}

__global__ void ball_i_k(const float* __restrict__ bih, const float* __restrict__ bhh,
                         float* __restrict__ ball) {
  int j = blockIdx.x * blockDim.x + threadIdx.x;
  if (j < 800) {
    int o = j >> 2, g = j & 3;
    float v;
    if (g == 0) v = bih[o] + bhh[o];
    else if (g == 1) v = bih[200 + o] + bhh[200 + o];
    else if (g == 2) v = bih[400 + o];
    else v = bhh[400 + o];
    ball[j] = v;
  }
}

__global__ void pack_lin8_k(const float* __restrict__ src, u8* __restrict__ dst,
                            int Nn, int K, int Kp) {
  int total = Nn * Kp;
  for (int i = blockIdx.x * blockDim.x + threadIdx.x; i < total; i += blockDim.x * gridDim.x) {
    int o = i / Kp, kp = i - o * Kp;
    dst[i] = (kp < K) ? f2fp8(src[(size_t)o * K + kp]) : (u8)0;
  }
}

__global__ void pack_w1c8_k(const float* __restrict__ src, u8* __restrict__ dst) {
  int total = 200 * 1056;
  for (int i = blockIdx.x * blockDim.x + threadIdx.x; i < total; i += blockDim.x * gridDim.x) {
    int o = i / 1056, r = i - o * 1056;
    int t = r / 352, kp = r - t * 352;
    dst[i] = (kp < 200) ? f2fp8(src[((size_t)o * 200 + kp) * 3 + t]) : (u8)0;
  }
}

__global__ void pack_wc18_k(const float* __restrict__ src, u8* __restrict__ dst) {
  int total = 300 * 1056;
  for (int i = blockIdx.x * blockDim.x + threadIdx.x; i < total; i += blockDim.x * gridDim.x) {
    int o = i / 1056, r = i - o * 1056;
    int t = r / 352, kp = r - t * 352;
    int ci = (kp < 224) ? (kp < 200 ? kp : -1) : ((kp - 224) < 100 ? 200 + (kp - 224) : -1);
    dst[i] = (ci >= 0) ? f2fp8(src[((size_t)o * 300 + ci) * 3 + t]) : (u8)0;
  }
}

// aggregation: wave per NODE; 16-lane group per etype; 2-deep pipelined edges
__global__ void agg8_k(const int* __restrict__ off_et, const int* __restrict__ deg_et,
                       const int* __restrict__ esrc, const u8* __restrict__ hqd,
                       u8* __restrict__ scat8, int N) {
  int gtid = blockIdx.x * blockDim.x + threadIdx.x;
  int wid = gtid >> 6, lane = threadIdx.x & 63;
  int nw = (blockDim.x * gridDim.x) >> 6;
  int sub = lane >> 4, l = lane & 15;
  for (int n = wid; n < N; n += nw) {
    u8* srow = scat8 + (size_t)n * 832;
    int rs = off_et[(size_t)sub * N + n];
    int d  = deg_et[(size_t)sub * N + n];
    f32x2 a2[8];
#pragma unroll
    for (int j = 0; j < 8; ++j) a2[j] = (f32x2)0.f;
    if (l < 13 && d > 0) {
      const size_t lo = (size_t)l * 16;
      uint4 v = *reinterpret_cast<const uint4*>(hqd + (size_t)esrc[rs] * 224 + lo);
      for (int i = 1; i < d; ++i) {
        uint4 vn = *reinterpret_cast<const uint4*>(hqd + (size_t)esrc[rs + i] * 224 + lo);
        a2[0] += __builtin_amdgcn_cvt_pk_f32_fp8(v.x, 0);
        a2[1] += __builtin_amdgcn_cvt_pk_f32_fp8(v.x, 1);
        a2[2] += __builtin_amdgcn_cvt_pk_f32_fp8(v.y, 0);
        a2[3] += __builtin_amdgcn_cvt_pk_f32_fp8(v.y, 1);
        a2[4] += __builtin_amdgcn_cvt_pk_f32_fp8(v.z, 0);
        a2[5] += __builtin_amdgcn_cvt_pk_f32_fp8(v.z, 1);
        a2[6] += __builtin_amdgcn_cvt_pk_f32_fp8(v.w, 0);
        a2[7] += __builtin_amdgcn_cvt_pk_f32_fp8(v.w, 1);
        v = vn;
      }
      a2[0] += __builtin_amdgcn_cvt_pk_f32_fp8(v.x, 0);
      a2[1] += __builtin_amdgcn_cvt_pk_f32_fp8(v.x, 1);
      a2[2] += __builtin_amdgcn_cvt_pk_f32_fp8(v.y, 0);
      a2[3] += __builtin_amdgcn_cvt_pk_f32_fp8(v.y, 1);
      a2[4] += __builtin_amdgcn_cvt_pk_f32_fp8(v.z, 0);
      a2[5] += __builtin_amdgcn_cvt_pk_f32_fp8(v.z, 1);
      a2[6] += __builtin_amdgcn_cvt_pk_f32_fp8(v.w, 0);
      a2[7] += __builtin_amdgcn_cvt_pk_f32_fp8(v.w, 1);
    }
    if (l < 13) {
      int d0, d1;
      d0 = __builtin_amdgcn_cvt_pk_fp8_f32(a2[0][0], a2[0][1], 0, false);
      d0 = __builtin_amdgcn_cvt_pk_fp8_f32(a2[1][0], a2[1][1], d0, true);
      d1 = __builtin_amdgcn_cvt_pk_fp8_f32(a2[2][0], a2[2][1], 0, false);
      d1 = __builtin_amdgcn_cvt_pk_fp8_f32(a2[3][0], a2[3][1], d1, true);
      *reinterpret_cast<uint2*>(srow + sub * 200 + l * 16) = make_uint2(d0, d1);
      if (l < 12) {
        int d2, d3;
        d2 = __builtin_amdgcn_cvt_pk_fp8_f32(a2[4][0], a2[4][1], 0, false);
        d2 = __builtin_amdgcn_cvt_pk_fp8_f32(a2[5][0], a2[5][1], d2, true);
        d3 = __builtin_amdgcn_cvt_pk_fp8_f32(a2[6][0], a2[6][1], 0, false);
        d3 = __builtin_amdgcn_cvt_pk_fp8_f32(a2[7][0], a2[7][1], d3, true);
        *reinterpret_cast<uint2*>(srow + sub * 200 + l * 16 + 8) = make_uint2(d2, d3);
      }
    }
    if (sub == 0 && l == 13) {
      float g0 = (float)deg_et[(size_t)0 * N + n];
      float g1 = (float)deg_et[(size_t)1 * N + n];
      float g2 = (float)deg_et[(size_t)2 * N + n];
      float g3 = (float)deg_et[(size_t)3 * N + n];
      int rr = __builtin_amdgcn_cvt_pk_fp8_f32(g0, g1, 0, false);
      rr = __builtin_amdgcn_cvt_pk_fp8_f32(g2, g3, rr, true);
      *reinterpret_cast<unsigned*>(srow + 800) = (unsigned)rr;
    }
    if (sub == 3 && l >= 1 && l <= 7)
      *reinterpret_cast<unsigned*>(srow + 804 + (l - 1) * 4) = 0;
  }
}

// ------- generic fp8 MFMA GEMM: Cq[M,0:Nn] = A@B^T, fp8 out, 256x128 tile ----
__global__ __launch_bounds__(512, 4) void gemm_a8(
    const u8* __restrict__ A, int lda,
    const u8* __restrict__ B, int ldb,
    u8* __restrict__ Cq, int ldcb, int npad,
    int M, int Nn, int K, int gyr) {
  const int gx = gridDim.x;
  int lin = blockIdx.y * gx + blockIdx.x;
  int k8 = lin & 7, j = lin >> 3;
  int band = gridDim.y >> 3;
  int yy = j / gx, xx = j - yy * gx;
  int by = k8 * band + yy;
  if (by >= gyr) return;
  const int m0 = by * 256, n0 = xx * 128;

  __shared__ __align__(16) u8 As[3 * 8192];
  __shared__ __align__(16) u8 Bs[3 * 4096];
  const int tid = threadIdx.x;
  const int lane = tid & 63;
  const int w = tid >> 6;
  const int wr = w >> 1, wc = w & 1;
  const int fr = lane & 15;
  const int g = lane >> 4;

  const int rowA = tid >> 1;
  const int cA = (tid & 1) ^ ((rowA >> 2) & 1);
  int gaA = m0 + rowA; if (gaA >= M) gaA = M - 1;
  const u8* pa = A + (size_t)gaA * lda + cA * 16;
  u8* lA = &As[(size_t)(w * 64) * 16];
  const int sB = w * 32 + (lane & 31);
  const int rowB = sB >> 1;
  const int cB = (sB & 1) ^ ((rowB >> 2) & 1);
  int gbB = n0 + rowB; if (gbB >= Nn) gbB = Nn - 1;
  const u8* pb = B + (size_t)gbB * ldb + cB * 16;
  u8* lB = &Bs[(size_t)(w * 32) * 16];
  const bool doB = (lane < 32);

  const int rdoff = (((g >> 1) ^ ((fr >> 2) & 1)) << 4) + ((g & 1) << 3);

  f32x4 acc[4][4] = {};
  const int nt = K >> 5;
  const int ABUF = 8192, BBUF = 4096;

  gload16(pa, lA);
  if (doB) gload16(pb, lB);
  pa += 32; pb += 32;
  if (nt > 1) {
    gload16(pa, lA + ABUF);
    if (doB) gload16(pb, lB + BBUF);
    pa += 32; pb += 32;
  }

  for (int t = 0; t < nt; ++t) {
    if (t + 1 < nt) asm volatile("s_waitcnt vmcnt(2)" ::: "memory");
    else            asm volatile("s_waitcnt vmcnt(0)" ::: "memory");
    __builtin_amdgcn_s_barrier();
    if (t + 2 < nt) {
      int bi = (t + 2) % 3;
      gload16(pa, lA + bi * ABUF);
      if (doB) gload16(pb, lB + bi * BBUF);
      pa += 32; pb += 32;
    }
    int ca = (t % 3) * ABUF, cbb = (t % 3) * BBUF;
    long af[4], bfv[4];
#pragma unroll
    for (int i = 0; i < 4; ++i) {
      int row = wr * 64 + i * 16 + fr;
      af[i] = *reinterpret_cast<const long*>(&As[ca + row * 32 + rdoff]);
    }
#pragma unroll
    for (int jj = 0; jj < 4; ++jj) {
      int row = wc * 64 + jj * 16 + fr;
      bfv[jj] = *reinterpret_cast<const long*>(&Bs[cbb + row * 32 + rdoff]);
    }
    __builtin_amdgcn_s_setprio(1);
#pragma unroll
    for (int i = 0; i < 4; ++i)
#pragma unroll
      for (int jj = 0; jj < 4; ++jj)
        acc[i][jj] = __builtin_amdgcn_mfma_f32_16x16x32_fp8_fp8(af[i], bfv[jj], acc[i][jj], 0, 0, 0);
    __builtin_amdgcn_s_setprio(0);
  }

  const int er = (lane >> 4) * 4;
  const int ec = lane & 15;
#pragma unroll
  for (int i = 0; i < 4; ++i) {
#pragma unroll
    for (int jj = 0; jj < 4; ++jj) {
      int n = n0 + wc * 64 + jj * 16 + ec;
#pragma unroll
      for (int r = 0; r < 4; ++r) {
        int m = m0 + wr * 64 + i * 16 + er + r;
        if (m >= M) continue;
        if (n < Nn) Cq[(size_t)m * ldcb + n] = f2fp8(acc[i][jj][r]);
        else if (n < npad) Cq[(size_t)m * ldcb + n] = (u8)0;
      }
    }
  }
}

// ------- fp8 gates GEMM + fused GRU; A = [aq | hq] two-source, K=448 ------
__global__ __launch_bounds__(512, 4) void gemm_gru8(
    const u8* __restrict__ Aa, const u8* __restrict__ Ah,
    const u8* __restrict__ B, int ldb,
    int M, const float* __restrict__ bias,
    u16* __restrict__ hb, u8* __restrict__ hqout, int gyr) {
  const int gx = gridDim.x;
  int lin = blockIdx.y * gx + blockIdx.x;
  int k8 = lin & 7, j = lin >> 3;
  int band = gridDim.y >> 3;
  int yy = j / gx, xx = j - yy * gx;
  int by = k8 * band + yy;
  if (by >= gyr) return;
  const int m0 = by * 256, n0 = xx * 128;
  const int Nn = 800;

  __shared__ __align__(16) u8 SM8[36864];   // K-loop 36864 B; epilogue 8x4608 B
  u8* As = SM8;
  u8* Bs = SM8 + 24576;
  const int tid = threadIdx.x;
  const int lane = tid & 63;
  const int w = tid >> 6;
  const int wr = w >> 1, wc = w & 1;
  const int fr = lane & 15;
  const int g = lane >> 4;

  const int rowA = tid >> 1;
  const int cA = (tid & 1) ^ ((rowA >> 2) & 1);
  int gaA = m0 + rowA; if (gaA >= M) gaA = M - 1;
  const u8* paA = Aa + (size_t)gaA * 224 + cA * 16;
  const u8* paH = Ah + (size_t)gaA * 224 + cA * 16;
  u8* lA = &As[(size_t)(w * 64) * 16];
  const int sB = w * 32 + (lane & 31);
  const int rowB = sB >> 1;
  const int cB = (sB & 1) ^ ((rowB >> 2) & 1);
  int gbB = n0 + rowB; if (gbB >= Nn) gbB = Nn - 1;
  const u8* pb = B + (size_t)gbB * ldb + cB * 16;
  u8* lB = &Bs[(size_t)(w * 32) * 16];
  const bool doB = (lane < 32);

  const int rdoff = (((g >> 1) ^ ((fr >> 2) & 1)) << 4) + ((g & 1) << 3);

  f32x4 acc[4][4] = {};
  const int nt = 14, kh = 7;
  const int ABUF = 8192, BBUF = 4096;

  gload16(paA, lA);
  if (doB) gload16(pb, lB);
  pb += 32;
  gload16(paA + 32, lA + ABUF);
  if (doB) gload16(pb, lB + BBUF);
  pb += 32;

  for (int t = 0; t < nt; ++t) {
    if (t + 1 < nt) asm volatile("s_waitcnt vmcnt(2)" ::: "memory");
    else            asm volatile("s_waitcnt vmcnt(0)" ::: "memory");
    __builtin_amdgcn_s_barrier();
    int tt = t + 2;
    if (tt < nt) {
      int bi = tt % 3;
      const u8* srcA = (tt < kh) ? (paA + tt * 32) : (paH + (tt - kh) * 32);
      gload16(srcA, lA + bi * ABUF);
      if (doB) gload16(pb, lB + bi * BBUF);
      pb += 32;
    }
    int ca = (t % 3) * ABUF, cbb = (t % 3) * BBUF;
    long af[4], bfv[4];
#pragma unroll
    for (int i = 0; i < 4; ++i) {
      int row = wr * 64 + i * 16 + fr;
      af[i] = *reinterpret_cast<const long*>(&As[ca + row * 32 + rdoff]);
    }
#pragma unroll
    for (int jj = 0; jj < 4; ++jj) {
      int row = wc * 64 + jj * 16 + fr;
      bfv[jj] = *reinterpret_cast<const long*>(&Bs[cbb + row * 32 + rdoff]);
    }
    __builtin_amdgcn_s_setprio(1);
#pragma unroll
    for (int i = 0; i < 4; ++i)
#pragma unroll
      for (int jj = 0; jj < 4; ++jj)
        acc[i][jj] = __builtin_amdgcn_mfma_f32_16x16x32_fp8_fp8(af[i], bfv[jj], acc[i][jj], 0, 0, 0);
    __builtin_amdgcn_s_setprio(0);
  }

  // ---- fused GRU epilogue: 4 quarter-passes, per-wave [64][18] f32 ----
  const int er = (lane >> 4) * 4;
  const int ec = lane & 15;
  __syncthreads();
  float* ep = (float*)(SM8) + (size_t)w * 1152;   // per-wave [64][18] f32 = 4608 B

#pragma unroll
  for (int jj = 0; jj < 4; ++jj) {
    {
      int n = n0 + wc * 64 + jj * 16 + ec;
      float bv = (n < 800) ? bias[n] : 0.f;
#pragma unroll
      for (int i = 0; i < 4; ++i)
#pragma unroll
        for (int r = 0; r < 4; ++r) {
          int row_loc = i * 16 + er + r;
          ep[row_loc * 18 + ec] = acc[i][jj][r] + bv;
        }
    }
    __syncthreads();
#pragma unroll
    for (int it = 0; it < 4; ++it) {
      int idx = it * 64 + lane;
      int row = idx >> 2, og = idx & 3;
      int n_base = n0 + wc * 64 + jj * 16 + og * 4;
      int m = m0 + wr * 64 + row;
      if (n_base < 800 && m < M) {
        f32x4 gv = *reinterpret_cast<f32x4*>(&ep[row * 18 + og * 4]);
        float rg = sigm(gv[0]);
        float zg = sigm(gv[1]);
        float x = gv[2] + rg * gv[3];
        float e2 = __expf(2.f * x);
        float nn = (e2 - 1.f) / (e2 + 1.f);
        int o = n_base >> 2;
        float hold = bf2f(hb[(size_t)m * 224 + o]);
        float hv = (1.f - zg) * nn + zg * hold;
        hb[(size_t)m * 224 + o] = f2bf(hv);
        hqout[(size_t)m * 224 + o] = f2fp8(hv);
      }
    }
    __syncthreads();
  }
}

// cmat8[n][352] fp8 = [hq(224) | feat(100) | 0(28)]
__global__ void cmat8_k(const u8* __restrict__ hq, const float* __restrict__ feat,
                        u8* __restrict__ c, int N) {
  int total = N * 352;
  for (int i = blockIdx.x * blockDim.x + threadIdx.x; i < total; i += blockDim.x * gridDim.x) {
    int n = i / 352, j = i - n * 352;
    u8 v;
    if (j < 224) v = hq[(size_t)n * 224 + j];
    else { int f = j - 224; v = (f < 100) ? f2fp8(feat[(size_t)n * 100 + f]) : (u8)0; }
    c[i] = v;
  }
}

// per-channel stats over fp8 X [L,C]
__global__ __launch_bounds__(1024) void bn_stats8_k(const u8* __restrict__ X, int L, int C,
                                                    float* __restrict__ stats) {
  const int Q = 1024 / C;
  const int T = Q * C;
  const int tid = threadIdx.x;
  float s = 0.f, q = 0.f;
  int c = 0;
  if (tid < T) {
    int qi = tid / C; c = tid - qi * C;
    for (size_t r = (size_t)blockIdx.x * Q + qi; r < (size_t)L; r += (size_t)gridDim.x * Q) {
      float v = fp82f(X[r * C + c]);
      s += v; q += v * v;
    }
  }
  __shared__ float sb[304], qb[304];
  for (int cc = tid; cc < C; cc += 1024) { sb[cc] = 0.f; qb[cc] = 0.f; }
  __syncthreads();
  if (tid < T) { atomicAdd(&sb[c], s); atomicAdd(&qb[c], q); }
  __syncthreads();
  for (int cc = tid; cc < C; cc += 1024) {
    atomicAdd(&stats[cc], sb[cc]);
    atomicAdd(&stats[C + cc], qb[cc]);
  }
}

__global__ void bn_fin_k(const float* __restrict__ stats, const float* __restrict__ g,
                         const float* __restrict__ b, int C, float Linv,
                         float* __restrict__ scsh) {
  int c = blockIdx.x * blockDim.x + threadIdx.x;
  if (c < C) {
    float mean = stats[c] * Linv;
    float var = stats[C + c] * Linv - mean * mean;
    float sc = g[c] * rsqrtf(var + 1e-5f);
    scsh[c] = sc;
    scsh[C + c] = b[c] - mean * sc;
  }
}

// fused bn+relu+maxpool: fp8 in -> fp8 out (padded to Cpad)
__global__ void pool_q8_k(const u8* __restrict__ X, int C, const float* __restrict__ scsh,
                          int kw, int stride, u8* __restrict__ Y, int Cpad, int Lout) {
  int total = Lout * Cpad;
  for (int i = blockIdx.x * blockDim.x + threadIdx.x; i < total; i += blockDim.x * gridDim.x) {
    int lp = i / Cpad, c = i - lp * Cpad;
    if (c >= C) { Y[i] = (u8)0; continue; }
    float sc = scsh[c], sh = scsh[C + c];
    int l0 = lp * stride;
    float m = 0.f;
    for (int wq = 0; wq < kw; ++wq)
      m = fmaxf(m, fmaf(fp82f(X[(size_t)(l0 + wq) * C + c]), sc, sh));
    Y[i] = f2fp8(m);
  }
}

// fused bn+relu+maxpool: fp8 in -> f32 out
__global__ void pool_f328_k(const u8* __restrict__ X, int C, const float* __restrict__ scsh,
                            int kw, int stride, float* __restrict__ Y, int Lout) {
  int total = Lout * C;
  for (int i = blockIdx.x * blockDim.x + threadIdx.x; i < total; i += blockDim.x * gridDim.x) {
    int lp = i / C, c = i - lp * C;
    float sc = scsh[c], sh = scsh[C + c];
    int l0 = lp * stride;
    float m = 0.f;
    for (int wq = 0; wq < kw; ++wq)
      m = fmaxf(m, fmaf(fp82f(X[(size_t)(l0 + wq) * C + c]), sc, sh));
    Y[i] = m;
  }
}

__global__ __launch_bounds__(256) void final_dot_k(
    const float* __restrict__ Y2, const float* __restrict__ Z2,
    const float* __restrict__ wy, const float* __restrict__ by,
    const float* __restrict__ wz, const float* __restrict__ bz,
    float* __restrict__ acc, int L) {
  float s0 = 0.f, s1 = 0.f;
  for (int lp = blockIdx.x * blockDim.x + threadIdx.x; lp < L; lp += blockDim.x * gridDim.x) {
    const float* y = Y2 + (size_t)lp * 200;
    const float* z = Z2 + (size_t)lp * 300;
    float d0 = 0.f, d1 = 0.f;
    for (int k = 0; k < 200; ++k) { float v = y[k]; d0 += v * wy[k]; d1 += v * wy[200 + k]; }
    float e0 = 0.f, e1 = 0.f;
    for (int k = 0; k < 300; ++k) { float v = z[k]; e0 += v * wz[k]; e1 += v * wz[300 + k]; }
    s0 += (d0 + by[0]) * (e0 + bz[0]);
    s1 += (d1 + by[1]) * (e1 + bz[1]);
  }
  __shared__ float r0[256], r1[256];
  r0[threadIdx.x] = s0; r1[threadIdx.x] = s1;
  __syncthreads();
  for (int off = 128; off > 0; off >>= 1) {
    if (threadIdx.x < off) { r0[threadIdx.x] += r0[threadIdx.x + off]; r1[threadIdx.x] += r1[threadIdx.x + off]; }
    __syncthreads();
  }
  if (threadIdx.x == 0) { atomicAdd(&acc[0], r0[0]); atomicAdd(&acc[1], r1[0]); }
}

__global__ void final_out_k(const float* __restrict__ acc, float invL, float* __restrict__ out) {
  int j = threadIdx.x;
  if (j < 2) out[j] = 1.f / (1.f + expf(-acc[j] * invL));
}

// ---------------- host ----------------

static inline void gemm8(hipStream_t st, const u8* A, int lda, const u8* B, int ldb,
                         u8* Cq, int ldcb, int npad, int M, int Nn, int K) {
  int ncols = (npad > Nn) ? npad : Nn;
  int gx = (ncols + 127) / 128;
  int gy = (M + 255) / 256;
  int gyp = ((gy + 7) / 8) * 8;
  dim3 g(gx, gyp);
  gemm_a8<<<g, 512, 0, st>>>(A, lda, B, ldb, Cq, ldcb, npad, M, Nn, K, gy);
}

extern "C" void kernel_launch(void* const* d_in, const int* in_sizes, int n_in,
                              void* d_out, int out_size, void* d_ws, size_t ws_size,
                              hipStream_t stream) {
  (void)n_in; (void)out_size;
  const float* feat    = (const float*)d_in[0];
  const int*   eix     = (const int*)d_in[1];
  const int*   etyp    = (const int*)d_in[2];
  const float* ggnnW   = (const float*)d_in[3];
  const float* ggnnB   = (const float*)d_in[4];
  const float* Wih     = (const float*)d_in[5];
  const float* Whh     = (const float*)d_in[6];
  const float* bih     = (const float*)d_in[7];
  const float* bhh     = (const float*)d_in[8];
  const float* conv1w  = (const float*)d_in[9];
  const float* conv2w  = (const float*)d_in[11];
  const float* convc1w = (const float*)d_in[13];
  const float* convc2w = (const float*)d_in[15];
  const float* bnyg    = (const float*)d_in[17];
  const float* bnyb    = (const float*)d_in[18];
  const float* bncg    = (const float*)d_in[19];
  const float* bncb    = (const float*)d_in[20];
  const float* mlpyw   = (const float*)d_in[21];
  const float* mlpyb   = (const float*)d_in[22];
  const float* mlpzw   = (const float*)d_in[23];
  const float* mlpzb   = (const float*)d_in[24];

  const int N = in_sizes[0] / 100;
  const int E = in_sizes[2];
  const int* src = eix;
  const int* dst = eix + E;

  char* base = (char*)d_ws;
  const size_t HB_B  = (size_t)N * 224 * 2;
  const size_t Q_B   = (size_t)N * 224;
  const int CH = (N + 1) / 2;
  const size_t SCR_B = (size_t)CH * 1664;

  u16* hb  = (u16*)base;
  u8*  aq  = (u8*)(base + HB_B);
  u8*  hq0 = aq + Q_B;
  u8*  hq1 = hq0 + Q_B;
  char* R1 = (char*)(hq1 + Q_B);
  char* WREG = R1 + SCR_B;

  u8*  Wcat8 = (u8*)WREG;
  u8*  Wall8 = Wcat8 + 166400;
  u8*  w1c8  = Wall8 + 358400;
  u8*  c2b8  = w1c8 + 211200;
  u8*  wc18  = c2b8 + 44800;
  u8*  wc28  = wc18 + 316800;
  float* ball  = (float*)(((uintptr_t)(wc28 + 96000) + 255) & ~(uintptr_t)255);
  float* stats = ball + 832;
  float* scsh  = stats + 600;
  float* acc2  = scsh + 600;
  int* deg_et = (int*)(acc2 + 8);
  int* off_et = deg_et + 4 * (size_t)N;
  int* cursor = off_et + 4 * (size_t)N;
  int* esrc   = cursor + 4 * (size_t)N;
  int* bsum   = esrc + E;
  const int L4 = 4 * N;
  const int NB = (L4 + 1023) / 1024;
  size_t need = (size_t)((char*)(bsum + NB) - base);

  if (ws_size < need) {
    fail_k<<<1, 64, 0, stream>>>((float*)d_out, -(float)(ws_size >> 20));
    return;
  }

  // ---- CSR build + packs ----
  hipMemsetAsync(deg_et, 0, sizeof(int) * 4 * (size_t)N, stream);
  init_hb_k<<<2048, 256, 0, stream>>>(feat, hb, N);
  init_hq_k<<<2048, 256, 0, stream>>>(feat, hq0, N);
  count_deg_k<<<2048, 256, 0, stream>>>(dst, etyp, deg_et, N, E);
  bsum_k<<<NB, 1024, 0, stream>>>(deg_et, bsum, L4);
  scanb_k<<<1, 1024, 0, stream>>>(bsum, NB);
  scan_fin_k<<<NB, 1024, 0, stream>>>(deg_et, bsum, off_et, L4);
  copy_int_k<<<512, 256, 0, stream>>>(off_et, cursor, L4);
  fill_src_k<<<2048, 256, 0, stream>>>(src, dst, etyp, cursor, esrc, N, E);
  pack_wcat8_k<<<651, 256, 0, stream>>>(ggnnW, ggnnB, Wcat8);
  pack_wall8_k<<<1400, 256, 0, stream>>>(Wih, Whh, Wall8);
  ball_i_k<<<4, 256, 0, stream>>>(bih, bhh, ball);
  pack_w1c8_k<<<825, 256, 0, stream>>>(conv1w, w1c8);
  pack_lin8_k<<<175, 256, 0, stream>>>(conv2w, c2b8, 200, 200, 224);
  pack_wc18_k<<<1238, 256, 0, stream>>>(convc1w, wc18);
  pack_lin8_k<<<375, 256, 0, stream>>>(convc2w, wc28, 300, 300, 320);

  // ---- GGNN 8 steps (ping-pong h tables) ----
  u8* scat8 = (u8*)R1;

  const int gy = (N + 255) / 256;
  const int gyp = ((gy + 7) / 8) * 8;

  u8* hqA = hq0;
  u8* hqB = hq1;
  for (int step = 0; step < 8; ++step) {
    agg8_k<<<4096, 256, 0, stream>>>(off_et, deg_et, esrc, hqA, scat8, N);
    gemm_a8<<<dim3(2, gyp), 512, 0, stream>>>(scat8, 832, Wcat8, 832,
                                              aq, 224, 224, N, 200, 832, gy);
    gemm_gru8<<<dim3(7, gyp), 512, 0, stream>>>(aq, hqA, Wall8, 448, N, ball,
                                                hb, hqB, gy);
    u8* t = hqA; hqA = hqB; hqB = t;
  }

  // ---- conv paths (all fp8 via gemm_a8) ----
  const int L1 = N - 2;
  const int L2 = (L1 - 3) / 2 + 1;
  const int L3 = (L2 - 2) / 2 + 1;

  u8* cmat8 = (u8*)R1;
  u8* out1q = (u8*)base;
  u8* y1q   = (u8*)base + 20500000;
  u8* out2q = (u8*)base + 32000000;
  float* Y2f = (float*)aq;
  u8* outc1q = hq0;
  u8* z1q    = (u8*)R1 + 37000000;
  u8* outc2q = (u8*)R1 + 54000000;
  float* Z2f = (float*)base;

  cmat8_k<<<4096, 256, 0, stream>>>(hqA, feat, cmat8, N);

  // Y path
  gemm8(stream, cmat8, 352, w1c8, 1056, out1q, 200, 200, L1, 200, 1056);
  hipMemsetAsync(stats, 0, sizeof(float) * 400, stream);
  bn_stats8_k<<<512, 1024, 0, stream>>>(out1q, L1, 200, stats);
  bn_fin_k<<<2, 256, 0, stream>>>(stats, bnyg, bnyb, 200, 1.f / (float)L1, scsh);
  pool_q8_k<<<2048, 256, 0, stream>>>(out1q, 200, scsh, 3, 2, y1q, 224, L2);

  gemm8(stream, y1q, 224, c2b8, 224, out2q, 200, 200, L2, 200, 224);
  hipMemsetAsync(stats, 0, sizeof(float) * 400, stream);
  bn_stats8_k<<<512, 1024, 0, stream>>>(out2q, L2, 200, stats);
  bn_fin_k<<<2, 256, 0, stream>>>(stats, bnyg, bnyb, 200, 1.f / (float)L2, scsh);
  pool_f328_k<<<2048, 256, 0, stream>>>(out2q, 200, scsh, 2, 2, Y2f, L3);

  // Z path
  gemm8(stream, cmat8, 352, wc18, 1056, outc1q, 300, 300, L1, 300, 1056);
  hipMemsetAsync(stats, 0, sizeof(float) * 600, stream);
  bn_stats8_k<<<512, 1024, 0, stream>>>(outc1q, L1, 300, stats);
  bn_fin_k<<<2, 256, 0, stream>>>(stats, bncg, bncb, 300, 1.f / (float)L1, scsh);
  pool_q8_k<<<2048, 256, 0, stream>>>(outc1q, 300, scsh, 3, 2, z1q, 320, L2);

  gemm8(stream, z1q, 320, wc28, 320, outc2q, 300, 300, L2, 300, 320);
  hipMemsetAsync(stats, 0, sizeof(float) * 600, stream);
  bn_stats8_k<<<512, 1024, 0, stream>>>(outc2q, L2, 300, stats);
  bn_fin_k<<<2, 256, 0, stream>>>(stats, bncg, bncb, 300, 1.f / (float)L2, scsh);
  pool_f328_k<<<2048, 256, 0, stream>>>(outc2q, 300, scsh, 2, 2, Z2f, L3);

  // ---- final MLP product + mean + sigmoid ----
  hipMemsetAsync(acc2, 0, sizeof(float) * 2, stream);
  final_dot_k<<<256, 256, 0, stream>>>(Y2f, Z2f, mlpyw, mlpyb, mlpzw, mlpzb, acc2, L3);
  final_out_k<<<1, 64, 0, stream>>>(acc2, 1.f / (float)L3, (float*)d_out);
}

// Round 21
// 2825.625 us; speedup vs baseline: 1.0460x; 1.0460x over previous
//
#include <hip/hip_runtime.h>
#include <cstddef>
#include <cstdint>

// ============================================================================
// DevignModel round 21: REVERT to round-19 kernel (2.80 ms known-good).
// r20's epilogue restructure regressed (occupancy was not LDS-limited;
// conflicts rose). This is r19 verbatim.
// ============================================================================

typedef unsigned short u16;
typedef unsigned char u8;
typedef __attribute__((ext_vector_type(8))) short bf16x8;
typedef __attribute__((ext_vector_type(4))) float f32x4;
typedef __attribute__((ext_vector_type(2))) float f32x2;

static __device__ __forceinline__ float bf2f(u16 u) {
  union { unsigned int i; float f; } v; v.i = ((unsigned int)u) << 16; return v.f;
}
static __device__ __forceinline__ u16 f2bf(float f) {
  union { float f; unsigned int i; } v; v.f = f;
  unsigned int r = v.i + 0x7FFFu + ((v.i >> 16) & 1u);
  return (u16)(r >> 16);
}
static __device__ __forceinline__ float sigm(float x) { return 1.f / (1.f + __expf(-x)); }
static __device__ __forceinline__ u8 f2fp8(float x) {
  return (u8)(__builtin_amdgcn_cvt_pk_fp8_f32(x, 0.f, 0, false) & 0xff);
}
static __device__ __forceinline__ float fp82f(u8 b) {
  f32x2 p = __builtin_amdgcn_cvt_pk_f32_fp8((unsigned)b, false);
  return p[0];
}

static __device__ __forceinline__ void gload16(const void* gp, void* lp) {
  __builtin_amdgcn_global_load_lds(
      (const __attribute__((address_space(1))) void*)gp,
      (__attribute__((address_space(3))) void*)lp, 16, 0, 0);
}

__global__ void fail_k(float* out, float code) { out[0] = code; out[1] = code; }

// hb[n][224] bf16 = [feat | 0]  (GRU hold state only)
__global__ void init_hb_k(const float* __restrict__ feat, u16* __restrict__ hb, int N) {
  int total = N * 224;
  for (int i = blockIdx.x * blockDim.x + threadIdx.x; i < total; i += blockDim.x * gridDim.x) {
    int n = i / 224, c = i - n * 224;
    hb[i] = (c < 100) ? f2bf(feat[(size_t)n * 100 + c]) : (u16)0;
  }
}

// dense hq0[n][224] fp8 = [feat | 0]
__global__ void init_hq_k(const float* __restrict__ feat, u8* __restrict__ hq0, int N) {
  int total = N * 224;
  for (int i = blockIdx.x * blockDim.x + threadIdx.x; i < total; i += blockDim.x * gridDim.x) {
    int n = i / 224, c = i - n * 224;
    hq0[i] = (c < 100) ? f2fp8(feat[(size_t)n * 100 + c]) : (u8)0;
  }
}

__global__ void count_deg_k(const int* __restrict__ dst, const int* __restrict__ et,
                            int* __restrict__ deg_et, int N, int E) {
  for (int e = blockIdx.x * blockDim.x + threadIdx.x; e < E; e += blockDim.x * gridDim.x)
    atomicAdd(&deg_et[et[e] * N + dst[e]], 1);
}

// ---- parallel exclusive scan (3 kernels) ----
__global__ __launch_bounds__(1024) void bsum_k(const int* __restrict__ cnt,
                                               int* __restrict__ bsum, int L) {
  __shared__ int buf[1024];
  int i = blockIdx.x * 1024 + threadIdx.x;
  buf[threadIdx.x] = (i < L) ? cnt[i] : 0;
  __syncthreads();
  for (int o = 512; o > 0; o >>= 1) {
    if (threadIdx.x < o) buf[threadIdx.x] += buf[threadIdx.x + o];
    __syncthreads();
  }
  if (threadIdx.x == 0) bsum[blockIdx.x] = buf[0];
}

__global__ __launch_bounds__(1024) void scanb_k(int* __restrict__ bsum, int nb) {
  __shared__ int buf[1024];
  int v = (threadIdx.x < nb) ? bsum[threadIdx.x] : 0;
  buf[threadIdx.x] = v;
  __syncthreads();
  for (int o = 1; o < 1024; o <<= 1) {
    int t = (threadIdx.x >= o) ? buf[threadIdx.x - o] : 0;
    __syncthreads();
    buf[threadIdx.x] += t;
    __syncthreads();
  }
  if (threadIdx.x < nb) bsum[threadIdx.x] = buf[threadIdx.x] - v;
}

__global__ __launch_bounds__(1024) void scan_fin_k(const int* __restrict__ cnt,
                                                   const int* __restrict__ bsum,
                                                   int* __restrict__ off, int L) {
  __shared__ int buf[1024];
  int i = blockIdx.x * 1024 + threadIdx.x;
  int v = (i < L) ? cnt[i] : 0;
  buf[threadIdx.x] = v;
  __syncthreads();
  for (int o = 1; o < 1024; o <<= 1) {
    int t = (threadIdx.x >= o) ? buf[threadIdx.x - o] : 0;
    __syncthreads();
    buf[threadIdx.x] += t;
    __syncthreads();
  }
  if (i < L) off[i] = buf[threadIdx.x] - v + bsum[blockIdx.x];
}

__global__ void copy_int_k(const int* __restrict__ a, int* __restrict__ b, int n) {
  for (int i = blockIdx.x * blockDim.x + threadIdx.x; i < n; i += blockDim.x * gridDim.x) b[i] = a[i];
}

__global__ void fill_src_k(const int* __restrict__ src, const int* __restrict__ dst,
                           const int* __restrict__ et, int* __restrict__ cursor,
                           int* __restrict__ esrc, int N, int E) {
  for (int e = blockIdx.x * blockDim.x + threadIdx.x; e < E; e += blockDim.x * gridDim.x) {
    int p = atomicAdd(&cursor[et[e] * N + dst[e]], 1);
    esrc[p] = src[e];
  }
}

// ---- weight packs (all fp8) ----

__global__ void pack_wcat8_k(const float* __restrict__ W, const float* __restrict__ gb,
                             u8* __restrict__ dst) {
  int total = 200 * 832;
  for (int i = blockIdx.x * blockDim.x + threadIdx.x; i < total; i += blockDim.x * gridDim.x) {
    int o = i / 832, kp = i - o * 832;
    float v = 0.f;
    if (kp < 800) { int k = kp / 200, kk = kp - k * 200; v = W[((size_t)k * 200 + o) * 200 + kk]; }
    else if (kp < 804) v = gb[(kp - 800) * 200 + o];
    dst[i] = f2fp8(v);
  }
}

// Wall8[800][448] fp8, gate-interleaved (row 4o+g)
__global__ void pack_wall8_k(const float* __restrict__ Wih, const float* __restrict__ Whh,
                             u8* __restrict__ dst) {
  int total = 800 * 448;
  for (int i = blockIdx.x * blockDim.x + threadIdx.x; i < total; i += blockDim.x * gridDim.x) {
    int jp = i / 448, kp = i - jp * 448;
    int o = jp >> 2, g = jp & 3;
    float v = 0.f;
    if (g == 0) {
      if (kp < 200) v = Wih[(size_t)o * 200 + kp];
      else if (kp >= 224 && kp < 424) v = Whh[(size_t)o * 200 + (kp - 224)];
    } else if (g == 1) {
      if (kp < 200) v = Wih[(size_t)(200 + o) * 200 + kp];
      else if (kp >= 224 && kp < 424) v = Whh[(size_t)(200 + o) * 200 + (kp - 224)];
    } else if (g == 2) {
      if (kp < 200) v = Wih[(size_t)(400 + o) * 200 + kp];
    } else {
      if (kp >= 224 && kp < 424) v = Whh[(size_t)(400 + o) * 200 + (kp - 224)];
    }
    dst[i] = f2fp8(v);
  }
}

__global__ void ball_i_k(const float* __restrict__ bih, const float* __restrict__ bhh,
                         float* __restrict__ ball) {
  int j = blockIdx.x * blockDim.x + threadIdx.x;
  if (j < 800) {
    int o = j >> 2, g = j & 3;
    float v;
    if (g == 0) v = bih[o] + bhh[o];
    else if (g == 1) v = bih[200 + o] + bhh[200 + o];
    else if (g == 2) v = bih[400 + o];
    else v = bhh[400 + o];
    ball[j] = v;
  }
}

__global__ void pack_lin8_k(const float* __restrict__ src, u8* __restrict__ dst,
                            int Nn, int K, int Kp) {
  int total = Nn * Kp;
  for (int i = blockIdx.x * blockDim.x + threadIdx.x; i < total; i += blockDim.x * gridDim.x) {
    int o = i / Kp, kp = i - o * Kp;
    dst[i] = (kp < K) ? f2fp8(src[(size_t)o * K + kp]) : (u8)0;
  }
}

__global__ void pack_w1c8_k(const float* __restrict__ src, u8* __restrict__ dst) {
  int total = 200 * 1056;
  for (int i = blockIdx.x * blockDim.x + threadIdx.x; i < total; i += blockDim.x * gridDim.x) {
    int o = i / 1056, r = i - o * 1056;
    int t = r / 352, kp = r - t * 352;
    dst[i] = (kp < 200) ? f2fp8(src[((size_t)o * 200 + kp) * 3 + t]) : (u8)0;
  }
}

__global__ void pack_wc18_k(const float* __restrict__ src, u8* __restrict__ dst) {
  int total = 300 * 1056;
  for (int i = blockIdx.x * blockDim.x + threadIdx.x; i < total; i += blockDim.x * gridDim.x) {
    int o = i / 1056, r = i - o * 1056;
    int t = r / 352, kp = r - t * 352;
    int ci = (kp < 224) ? (kp < 200 ? kp : -1) : ((kp - 224) < 100 ? 200 + (kp - 224) : -1);
    dst[i] = (ci >= 0) ? f2fp8(src[((size_t)o * 300 + ci) * 3 + t]) : (u8)0;
  }
}

// aggregation: wave per NODE; 16-lane group per etype; 2-deep pipelined edges
__global__ void agg8_k(const int* __restrict__ off_et, const int* __restrict__ deg_et,
                       const int* __restrict__ esrc, const u8* __restrict__ hqd,
                       u8* __restrict__ scat8, int N) {
  int gtid = blockIdx.x * blockDim.x + threadIdx.x;
  int wid = gtid >> 6, lane = threadIdx.x & 63;
  int nw = (blockDim.x * gridDim.x) >> 6;
  int sub = lane >> 4, l = lane & 15;
  for (int n = wid; n < N; n += nw) {
    u8* srow = scat8 + (size_t)n * 832;
    int rs = off_et[(size_t)sub * N + n];
    int d  = deg_et[(size_t)sub * N + n];
    f32x2 a2[8];
#pragma unroll
    for (int j = 0; j < 8; ++j) a2[j] = (f32x2)0.f;
    if (l < 13 && d > 0) {
      const size_t lo = (size_t)l * 16;
      uint4 v = *reinterpret_cast<const uint4*>(hqd + (size_t)esrc[rs] * 224 + lo);
      for (int i = 1; i < d; ++i) {
        uint4 vn = *reinterpret_cast<const uint4*>(hqd + (size_t)esrc[rs + i] * 224 + lo);
        a2[0] += __builtin_amdgcn_cvt_pk_f32_fp8(v.x, 0);
        a2[1] += __builtin_amdgcn_cvt_pk_f32_fp8(v.x, 1);
        a2[2] += __builtin_amdgcn_cvt_pk_f32_fp8(v.y, 0);
        a2[3] += __builtin_amdgcn_cvt_pk_f32_fp8(v.y, 1);
        a2[4] += __builtin_amdgcn_cvt_pk_f32_fp8(v.z, 0);
        a2[5] += __builtin_amdgcn_cvt_pk_f32_fp8(v.z, 1);
        a2[6] += __builtin_amdgcn_cvt_pk_f32_fp8(v.w, 0);
        a2[7] += __builtin_amdgcn_cvt_pk_f32_fp8(v.w, 1);
        v = vn;
      }
      a2[0] += __builtin_amdgcn_cvt_pk_f32_fp8(v.x, 0);
      a2[1] += __builtin_amdgcn_cvt_pk_f32_fp8(v.x, 1);
      a2[2] += __builtin_amdgcn_cvt_pk_f32_fp8(v.y, 0);
      a2[3] += __builtin_amdgcn_cvt_pk_f32_fp8(v.y, 1);
      a2[4] += __builtin_amdgcn_cvt_pk_f32_fp8(v.z, 0);
      a2[5] += __builtin_amdgcn_cvt_pk_f32_fp8(v.z, 1);
      a2[6] += __builtin_amdgcn_cvt_pk_f32_fp8(v.w, 0);
      a2[7] += __builtin_amdgcn_cvt_pk_f32_fp8(v.w, 1);
    }
    if (l < 13) {
      int d0, d1;
      d0 = __builtin_amdgcn_cvt_pk_fp8_f32(a2[0][0], a2[0][1], 0, false);
      d0 = __builtin_amdgcn_cvt_pk_fp8_f32(a2[1][0], a2[1][1], d0, true);
      d1 = __builtin_amdgcn_cvt_pk_fp8_f32(a2[2][0], a2[2][1], 0, false);
      d1 = __builtin_amdgcn_cvt_pk_fp8_f32(a2[3][0], a2[3][1], d1, true);
      *reinterpret_cast<uint2*>(srow + sub * 200 + l * 16) = make_uint2(d0, d1);
      if (l < 12) {
        int d2, d3;
        d2 = __builtin_amdgcn_cvt_pk_fp8_f32(a2[4][0], a2[4][1], 0, false);
        d2 = __builtin_amdgcn_cvt_pk_fp8_f32(a2[5][0], a2[5][1], d2, true);
        d3 = __builtin_amdgcn_cvt_pk_fp8_f32(a2[6][0], a2[6][1], 0, false);
        d3 = __builtin_amdgcn_cvt_pk_fp8_f32(a2[7][0], a2[7][1], d3, true);
        *reinterpret_cast<uint2*>(srow + sub * 200 + l * 16 + 8) = make_uint2(d2, d3);
      }
    }
    if (sub == 0 && l == 13) {
      float g0 = (float)deg_et[(size_t)0 * N + n];
      float g1 = (float)deg_et[(size_t)1 * N + n];
      float g2 = (float)deg_et[(size_t)2 * N + n];
      float g3 = (float)deg_et[(size_t)3 * N + n];
      int rr = __builtin_amdgcn_cvt_pk_fp8_f32(g0, g1, 0, false);
      rr = __builtin_amdgcn_cvt_pk_fp8_f32(g2, g3, rr, true);
      *reinterpret_cast<unsigned*>(srow + 800) = (unsigned)rr;
    }
    if (sub == 3 && l >= 1 && l <= 7)
      *reinterpret_cast<unsigned*>(srow + 804 + (l - 1) * 4) = 0;
  }
}

// ------- generic fp8 MFMA GEMM: Cq[M,0:Nn] = A@B^T, fp8 out, 256x128 tile ----
__global__ __launch_bounds__(512, 4) void gemm_a8(
    const u8* __restrict__ A, int lda,
    const u8* __restrict__ B, int ldb,
    u8* __restrict__ Cq, int ldcb, int npad,
    int M, int Nn, int K, int gyr) {
  const int gx = gridDim.x;
  int lin = blockIdx.y * gx + blockIdx.x;
  int k8 = lin & 7, j = lin >> 3;
  int band = gridDim.y >> 3;
  int yy = j / gx, xx = j - yy * gx;
  int by = k8 * band + yy;
  if (by >= gyr) return;
  const int m0 = by * 256, n0 = xx * 128;

  __shared__ __align__(16) u8 As[3 * 8192];
  __shared__ __align__(16) u8 Bs[3 * 4096];
  const int tid = threadIdx.x;
  const int lane = tid & 63;
  const int w = tid >> 6;
  const int wr = w >> 1, wc = w & 1;
  const int fr = lane & 15;
  const int g = lane >> 4;

  const int rowA = tid >> 1;
  const int cA = (tid & 1) ^ ((rowA >> 2) & 1);
  int gaA = m0 + rowA; if (gaA >= M) gaA = M - 1;
  const u8* pa = A + (size_t)gaA * lda + cA * 16;
  u8* lA = &As[(size_t)(w * 64) * 16];
  const int sB = w * 32 + (lane & 31);
  const int rowB = sB >> 1;
  const int cB = (sB & 1) ^ ((rowB >> 2) & 1);
  int gbB = n0 + rowB; if (gbB >= Nn) gbB = Nn - 1;
  const u8* pb = B + (size_t)gbB * ldb + cB * 16;
  u8* lB = &Bs[(size_t)(w * 32) * 16];
  const bool doB = (lane < 32);

  const int rdoff = (((g >> 1) ^ ((fr >> 2) & 1)) << 4) + ((g & 1) << 3);

  f32x4 acc[4][4] = {};
  const int nt = K >> 5;
  const int ABUF = 8192, BBUF = 4096;

  gload16(pa, lA);
  if (doB) gload16(pb, lB);
  pa += 32; pb += 32;
  if (nt > 1) {
    gload16(pa, lA + ABUF);
    if (doB) gload16(pb, lB + BBUF);
    pa += 32; pb += 32;
  }

  for (int t = 0; t < nt; ++t) {
    if (t + 1 < nt) asm volatile("s_waitcnt vmcnt(2)" ::: "memory");
    else            asm volatile("s_waitcnt vmcnt(0)" ::: "memory");
    __builtin_amdgcn_s_barrier();
    if (t + 2 < nt) {
      int bi = (t + 2) % 3;
      gload16(pa, lA + bi * ABUF);
      if (doB) gload16(pb, lB + bi * BBUF);
      pa += 32; pb += 32;
    }
    int ca = (t % 3) * ABUF, cbb = (t % 3) * BBUF;
    long af[4], bfv[4];
#pragma unroll
    for (int i = 0; i < 4; ++i) {
      int row = wr * 64 + i * 16 + fr;
      af[i] = *reinterpret_cast<const long*>(&As[ca + row * 32 + rdoff]);
    }
#pragma unroll
    for (int jj = 0; jj < 4; ++jj) {
      int row = wc * 64 + jj * 16 + fr;
      bfv[jj] = *reinterpret_cast<const long*>(&Bs[cbb + row * 32 + rdoff]);
    }
    __builtin_amdgcn_s_setprio(1);
#pragma unroll
    for (int i = 0; i < 4; ++i)
#pragma unroll
      for (int jj = 0; jj < 4; ++jj)
        acc[i][jj] = __builtin_amdgcn_mfma_f32_16x16x32_fp8_fp8(af[i], bfv[jj], acc[i][jj], 0, 0, 0);
    __builtin_amdgcn_s_setprio(0);
  }

  const int er = (lane >> 4) * 4;
  const int ec = lane & 15;
#pragma unroll
  for (int i = 0; i < 4; ++i) {
#pragma unroll
    for (int jj = 0; jj < 4; ++jj) {
      int n = n0 + wc * 64 + jj * 16 + ec;
#pragma unroll
      for (int r = 0; r < 4; ++r) {
        int m = m0 + wr * 64 + i * 16 + er + r;
        if (m >= M) continue;
        if (n < Nn) Cq[(size_t)m * ldcb + n] = f2fp8(acc[i][jj][r]);
        else if (n < npad) Cq[(size_t)m * ldcb + n] = (u8)0;
      }
    }
  }
}

// ------- fp8 gates GEMM + fused GRU; A = [aq | hq] two-source, K=448 ------
__global__ __launch_bounds__(512, 4) void gemm_gru8(
    const u8* __restrict__ Aa, const u8* __restrict__ Ah,
    const u8* __restrict__ B, int ldb,
    int M, const float* __restrict__ bias,
    u16* __restrict__ hb, u8* __restrict__ hqout, int gyr) {
  const int gx = gridDim.x;
  int lin = blockIdx.y * gx + blockIdx.x;
  int k8 = lin & 7, j = lin >> 3;
  int band = gridDim.y >> 3;
  int yy = j / gx, xx = j - yy * gx;
  int by = k8 * band + yy;
  if (by >= gyr) return;
  const int m0 = by * 256, n0 = xx * 128;
  const int Nn = 800;

  __shared__ __align__(16) u8 SM8[73728];
  u8* As = SM8;
  u8* Bs = SM8 + 24576;
  const int tid = threadIdx.x;
  const int lane = tid & 63;
  const int w = tid >> 6;
  const int wr = w >> 1, wc = w & 1;
  const int fr = lane & 15;
  const int g = lane >> 4;

  const int rowA = tid >> 1;
  const int cA = (tid & 1) ^ ((rowA >> 2) & 1);
  int gaA = m0 + rowA; if (gaA >= M) gaA = M - 1;
  const u8* paA = Aa + (size_t)gaA * 224 + cA * 16;
  const u8* paH = Ah + (size_t)gaA * 224 + cA * 16;
  u8* lA = &As[(size_t)(w * 64) * 16];
  const int sB = w * 32 + (lane & 31);
  const int rowB = sB >> 1;
  const int cB = (sB & 1) ^ ((rowB >> 2) & 1);
  int gbB = n0 + rowB; if (gbB >= Nn) gbB = Nn - 1;
  const u8* pb = B + (size_t)gbB * ldb + cB * 16;
  u8* lB = &Bs[(size_t)(w * 32) * 16];
  const bool doB = (lane < 32);

  const int rdoff = (((g >> 1) ^ ((fr >> 2) & 1)) << 4) + ((g & 1) << 3);

  f32x4 acc[4][4] = {};
  const int nt = 14, kh = 7;
  const int ABUF = 8192, BBUF = 4096;

  gload16(paA, lA);
  if (doB) gload16(pb, lB);
  pb += 32;
  gload16(paA + 32, lA + ABUF);
  if (doB) gload16(pb, lB + BBUF);
  pb += 32;

  for (int t = 0; t < nt; ++t) {
    if (t + 1 < nt) asm volatile("s_waitcnt vmcnt(2)" ::: "memory");
    else            asm volatile("s_waitcnt vmcnt(0)" ::: "memory");
    __builtin_amdgcn_s_barrier();
    int tt = t + 2;
    if (tt < nt) {
      int bi = tt % 3;
      const u8* srcA = (tt < kh) ? (paA + tt * 32) : (paH + (tt - kh) * 32);
      gload16(srcA, lA + bi * ABUF);
      if (doB) gload16(pb, lB + bi * BBUF);
      pb += 32;
    }
    int ca = (t % 3) * ABUF, cbb = (t % 3) * BBUF;
    long af[4], bfv[4];
#pragma unroll
    for (int i = 0; i < 4; ++i) {
      int row = wr * 64 + i * 16 + fr;
      af[i] = *reinterpret_cast<const long*>(&As[ca + row * 32 + rdoff]);
    }
#pragma unroll
    for (int jj = 0; jj < 4; ++jj) {
      int row = wc * 64 + jj * 16 + fr;
      bfv[jj] = *reinterpret_cast<const long*>(&Bs[cbb + row * 32 + rdoff]);
    }
    __builtin_amdgcn_s_setprio(1);
#pragma unroll
    for (int i = 0; i < 4; ++i)
#pragma unroll
      for (int jj = 0; jj < 4; ++jj)
        acc[i][jj] = __builtin_amdgcn_mfma_f32_16x16x32_fp8_fp8(af[i], bfv[jj], acc[i][jj], 0, 0, 0);
    __builtin_amdgcn_s_setprio(0);
  }

  // ---- fused GRU epilogue (LDS stride 36 f32) ----
  const int er = (lane >> 4) * 4;
  const int ec = lane & 15;
  __syncthreads();
  float* ep = (float*)(SM8) + (size_t)w * 2304;

  for (int hh = 0; hh < 2; ++hh) {
#pragma unroll
    for (int jj2 = 0; jj2 < 2; ++jj2) {
      int jj = hh * 2 + jj2;
      int n = n0 + wc * 64 + jj * 16 + ec;
      float bv = (n < 800) ? bias[n] : 0.f;
#pragma unroll
      for (int i = 0; i < 4; ++i)
#pragma unroll
        for (int r = 0; r < 4; ++r) {
          int row_loc = i * 16 + er + r;
          ep[row_loc * 36 + jj2 * 16 + ec] = acc[i][jj][r] + bv;
        }
    }
    __syncthreads();
#pragma unroll
    for (int p = 0; p < 8; ++p) {
      int idx = p * 64 + lane;
      int row = idx >> 3, og = idx & 7;
      int n_base = n0 + wc * 64 + hh * 32 + og * 4;
      int m = m0 + wr * 64 + row;
      if (n_base < 800 && m < M) {
        f32x4 gv = *reinterpret_cast<f32x4*>(&ep[row * 36 + og * 4]);
        float rg = sigm(gv[0]);
        float zg = sigm(gv[1]);
        float x = gv[2] + rg * gv[3];
        float e2 = __expf(2.f * x);
        float nn = (e2 - 1.f) / (e2 + 1.f);
        int o = n_base >> 2;
        float hold = bf2f(hb[(size_t)m * 224 + o]);
        float hv = (1.f - zg) * nn + zg * hold;
        hb[(size_t)m * 224 + o] = f2bf(hv);
        hqout[(size_t)m * 224 + o] = f2fp8(hv);
      }
    }
    __syncthreads();
  }
}

// cmat8[n][352] fp8 = [hq(224) | feat(100) | 0(28)]
__global__ void cmat8_k(const u8* __restrict__ hq, const float* __restrict__ feat,
                        u8* __restrict__ c, int N) {
  int total = N * 352;
  for (int i = blockIdx.x * blockDim.x + threadIdx.x; i < total; i += blockDim.x * gridDim.x) {
    int n = i / 352, j = i - n * 352;
    u8 v;
    if (j < 224) v = hq[(size_t)n * 224 + j];
    else { int f = j - 224; v = (f < 100) ? f2fp8(feat[(size_t)n * 100 + f]) : (u8)0; }
    c[i] = v;
  }
}

// per-channel stats over fp8 X [L,C]
__global__ __launch_bounds__(1024) void bn_stats8_k(const u8* __restrict__ X, int L, int C,
                                                    float* __restrict__ stats) {
  const int Q = 1024 / C;
  const int T = Q * C;
  const int tid = threadIdx.x;
  float s = 0.f, q = 0.f;
  int c = 0;
  if (tid < T) {
    int qi = tid / C; c = tid - qi * C;
    for (size_t r = (size_t)blockIdx.x * Q + qi; r < (size_t)L; r += (size_t)gridDim.x * Q) {
      float v = fp82f(X[r * C + c]);
      s += v; q += v * v;
    }
  }
  __shared__ float sb[304], qb[304];
  for (int cc = tid; cc < C; cc += 1024) { sb[cc] = 0.f; qb[cc] = 0.f; }
  __syncthreads();
  if (tid < T) { atomicAdd(&sb[c], s); atomicAdd(&qb[c], q); }
  __syncthreads();
  for (int cc = tid; cc < C; cc += 1024) {
    atomicAdd(&stats[cc], sb[cc]);
    atomicAdd(&stats[C + cc], qb[cc]);
  }
}

__global__ void bn_fin_k(const float* __restrict__ stats, const float* __restrict__ g,
                         const float* __restrict__ b, int C, float Linv,
                         float* __restrict__ scsh) {
  int c = blockIdx.x * blockDim.x + threadIdx.x;
  if (c < C) {
    float mean = stats[c] * Linv;
    float var = stats[C + c] * Linv - mean * mean;
    float sc = g[c] * rsqrtf(var + 1e-5f);
    scsh[c] = sc;
    scsh[C + c] = b[c] - mean * sc;
  }
}

// fused bn+relu+maxpool: fp8 in -> fp8 out (padded to Cpad)
__global__ void pool_q8_k(const u8* __restrict__ X, int C, const float* __restrict__ scsh,
                          int kw, int stride, u8* __restrict__ Y, int Cpad, int Lout) {
  int total = Lout * Cpad;
  for (int i = blockIdx.x * blockDim.x + threadIdx.x; i < total; i += blockDim.x * gridDim.x) {
    int lp = i / Cpad, c = i - lp * Cpad;
    if (c >= C) { Y[i] = (u8)0; continue; }
    float sc = scsh[c], sh = scsh[C + c];
    int l0 = lp * stride;
    float m = 0.f;
    for (int wq = 0; wq < kw; ++wq)
      m = fmaxf(m, fmaf(fp82f(X[(size_t)(l0 + wq) * C + c]), sc, sh));
    Y[i] = f2fp8(m);
  }
}

// fused bn+relu+maxpool: fp8 in -> f32 out
__global__ void pool_f328_k(const u8* __restrict__ X, int C, const float* __restrict__ scsh,
                            int kw, int stride, float* __restrict__ Y, int Lout) {
  int total = Lout * C;
  for (int i = blockIdx.x * blockDim.x + threadIdx.x; i < total; i += blockDim.x * gridDim.x) {
    int lp = i / C, c = i - lp * C;
    float sc = scsh[c], sh = scsh[C + c];
    int l0 = lp * stride;
    float m = 0.f;
    for (int wq = 0; wq < kw; ++wq)
      m = fmaxf(m, fmaf(fp82f(X[(size_t)(l0 + wq) * C + c]), sc, sh));
    Y[i] = m;
  }
}

__global__ __launch_bounds__(256) void final_dot_k(
    const float* __restrict__ Y2, const float* __restrict__ Z2,
    const float* __restrict__ wy, const float* __restrict__ by,
    const float* __restrict__ wz, const float* __restrict__ bz,
    float* __restrict__ acc, int L) {
  float s0 = 0.f, s1 = 0.f;
  for (int lp = blockIdx.x * blockDim.x + threadIdx.x; lp < L; lp += blockDim.x * gridDim.x) {
    const float* y = Y2 + (size_t)lp * 200;
    const float* z = Z2 + (size_t)lp * 300;
    float d0 = 0.f, d1 = 0.f;
    for (int k = 0; k < 200; ++k) { float v = y[k]; d0 += v * wy[k]; d1 += v * wy[200 + k]; }
    float e0 = 0.f, e1 = 0.f;
    for (int k = 0; k < 300; ++k) { float v = z[k]; e0 += v * wz[k]; e1 += v * wz[300 + k]; }
    s0 += (d0 + by[0]) * (e0 + bz[0]);
    s1 += (d1 + by[1]) * (e1 + bz[1]);
  }
  __shared__ float r0[256], r1[256];
  r0[threadIdx.x] = s0; r1[threadIdx.x] = s1;
  __syncthreads();
  for (int off = 128; off > 0; off >>= 1) {
    if (threadIdx.x < off) { r0[threadIdx.x] += r0[threadIdx.x + off]; r1[threadIdx.x] += r1[threadIdx.x + off]; }
    __syncthreads();
  }
  if (threadIdx.x == 0) { atomicAdd(&acc[0], r0[0]); atomicAdd(&acc[1], r1[0]); }
}

__global__ void final_out_k(const float* __restrict__ acc, float invL, float* __restrict__ out) {
  int j = threadIdx.x;
  if (j < 2) out[j] = 1.f / (1.f + expf(-acc[j] * invL));
}

// ---------------- host ----------------

static inline void gemm8(hipStream_t st, const u8* A, int lda, const u8* B, int ldb,
                         u8* Cq, int ldcb, int npad, int M, int Nn, int K) {
  int ncols = (npad > Nn) ? npad : Nn;
  int gx = (ncols + 127) / 128;
  int gy = (M + 255) / 256;
  int gyp = ((gy + 7) / 8) * 8;
  dim3 g(gx, gyp);
  gemm_a8<<<g, 512, 0, st>>>(A, lda, B, ldb, Cq, ldcb, npad, M, Nn, K, gy);
}

extern "C" void kernel_launch(void* const* d_in, const int* in_sizes, int n_in,
                              void* d_out, int out_size, void* d_ws, size_t ws_size,
                              hipStream_t stream) {
  (void)n_in; (void)out_size;
  const float* feat    = (const float*)d_in[0];
  const int*   eix     = (const int*)d_in[1];
  const int*   etyp    = (const int*)d_in[2];
  const float* ggnnW   = (const float*)d_in[3];
  const float* ggnnB   = (const float*)d_in[4];
  const float* Wih     = (const float*)d_in[5];
  const float* Whh     = (const float*)d_in[6];
  const float* bih     = (const float*)d_in[7];
  const float* bhh     = (const float*)d_in[8];
  const float* conv1w  = (const float*)d_in[9];
  const float* conv2w  = (const float*)d_in[11];
  const float* convc1w = (const float*)d_in[13];
  const float* convc2w = (const float*)d_in[15];
  const float* bnyg    = (const float*)d_in[17];
  const float* bnyb    = (const float*)d_in[18];
  const float* bncg    = (const float*)d_in[19];
  const float* bncb    = (const float*)d_in[20];
  const float* mlpyw   = (const float*)d_in[21];
  const float* mlpyb   = (const float*)d_in[22];
  const float* mlpzw   = (const float*)d_in[23];
  const float* mlpzb   = (const float*)d_in[24];

  const int N = in_sizes[0] / 100;
  const int E = in_sizes[2];
  const int* src = eix;
  const int* dst = eix + E;

  char* base = (char*)d_ws;
  const size_t HB_B  = (size_t)N * 224 * 2;
  const size_t Q_B   = (size_t)N * 224;
  const int CH = (N + 1) / 2;
  const size_t SCR_B = (size_t)CH * 1664;

  u16* hb  = (u16*)base;
  u8*  aq  = (u8*)(base + HB_B);
  u8*  hq0 = aq + Q_B;
  u8*  hq1 = hq0 + Q_B;
  char* R1 = (char*)(hq1 + Q_B);
  char* WREG = R1 + SCR_B;

  u8*  Wcat8 = (u8*)WREG;
  u8*  Wall8 = Wcat8 + 166400;
  u8*  w1c8  = Wall8 + 358400;
  u8*  c2b8  = w1c8 + 211200;
  u8*  wc18  = c2b8 + 44800;
  u8*  wc28  = wc18 + 316800;
  float* ball  = (float*)(((uintptr_t)(wc28 + 96000) + 255) & ~(uintptr_t)255);
  float* stats = ball + 832;
  float* scsh  = stats + 600;
  float* acc2  = scsh + 600;
  int* deg_et = (int*)(acc2 + 8);
  int* off_et = deg_et + 4 * (size_t)N;
  int* cursor = off_et + 4 * (size_t)N;
  int* esrc   = cursor + 4 * (size_t)N;
  int* bsum   = esrc + E;
  const int L4 = 4 * N;
  const int NB = (L4 + 1023) / 1024;
  size_t need = (size_t)((char*)(bsum + NB) - base);

  if (ws_size < need) {
    fail_k<<<1, 64, 0, stream>>>((float*)d_out, -(float)(ws_size >> 20));
    return;
  }

  // ---- CSR build + packs ----
  hipMemsetAsync(deg_et, 0, sizeof(int) * 4 * (size_t)N, stream);
  init_hb_k<<<2048, 256, 0, stream>>>(feat, hb, N);
  init_hq_k<<<2048, 256, 0, stream>>>(feat, hq0, N);
  count_deg_k<<<2048, 256, 0, stream>>>(dst, etyp, deg_et, N, E);
  bsum_k<<<NB, 1024, 0, stream>>>(deg_et, bsum, L4);
  scanb_k<<<1, 1024, 0, stream>>>(bsum, NB);
  scan_fin_k<<<NB, 1024, 0, stream>>>(deg_et, bsum, off_et, L4);
  copy_int_k<<<512, 256, 0, stream>>>(off_et, cursor, L4);
  fill_src_k<<<2048, 256, 0, stream>>>(src, dst, etyp, cursor, esrc, N, E);
  pack_wcat8_k<<<651, 256, 0, stream>>>(ggnnW, ggnnB, Wcat8);
  pack_wall8_k<<<1400, 256, 0, stream>>>(Wih, Whh, Wall8);
  ball_i_k<<<4, 256, 0, stream>>>(bih, bhh, ball);
  pack_w1c8_k<<<825, 256, 0, stream>>>(conv1w, w1c8);
  pack_lin8_k<<<175, 256, 0, stream>>>(conv2w, c2b8, 200, 200, 224);
  pack_wc18_k<<<1238, 256, 0, stream>>>(convc1w, wc18);
  pack_lin8_k<<<375, 256, 0, stream>>>(convc2w, wc28, 300, 300, 320);

  // ---- GGNN 8 steps (ping-pong h tables) ----
  u8* scat8 = (u8*)R1;

  const int gy = (N + 255) / 256;
  const int gyp = ((gy + 7) / 8) * 8;

  u8* hqA = hq0;
  u8* hqB = hq1;
  for (int step = 0; step < 8; ++step) {
    agg8_k<<<4096, 256, 0, stream>>>(off_et, deg_et, esrc, hqA, scat8, N);
    gemm_a8<<<dim3(2, gyp), 512, 0, stream>>>(scat8, 832, Wcat8, 832,
                                              aq, 224, 224, N, 200, 832, gy);
    gemm_gru8<<<dim3(7, gyp), 512, 0, stream>>>(aq, hqA, Wall8, 448, N, ball,
                                                hb, hqB, gy);
    u8* t = hqA; hqA = hqB; hqB = t;
  }

  // ---- conv paths (all fp8 via gemm_a8) ----
  const int L1 = N - 2;
  const int L2 = (L1 - 3) / 2 + 1;
  const int L3 = (L2 - 2) / 2 + 1;

  u8* cmat8 = (u8*)R1;
  u8* out1q = (u8*)base;
  u8* y1q   = (u8*)base + 20500000;
  u8* out2q = (u8*)base + 32000000;
  float* Y2f = (float*)aq;
  u8* outc1q = hq0;
  u8* z1q    = (u8*)R1 + 37000000;
  u8* outc2q = (u8*)R1 + 54000000;
  float* Z2f = (float*)base;

  cmat8_k<<<4096, 256, 0, stream>>>(hqA, feat, cmat8, N);

  // Y path
  gemm8(stream, cmat8, 352, w1c8, 1056, out1q, 200, 200, L1, 200, 1056);
  hipMemsetAsync(stats, 0, sizeof(float) * 400, stream);
  bn_stats8_k<<<512, 1024, 0, stream>>>(out1q, L1, 200, stats);
  bn_fin_k<<<2, 256, 0, stream>>>(stats, bnyg, bnyb, 200, 1.f / (float)L1, scsh);
  pool_q8_k<<<2048, 256, 0, stream>>>(out1q, 200, scsh, 3, 2, y1q, 224, L2);

  gemm8(stream, y1q, 224, c2b8, 224, out2q, 200, 200, L2, 200, 224);
  hipMemsetAsync(stats, 0, sizeof(float) * 400, stream);
  bn_stats8_k<<<512, 1024, 0, stream>>>(out2q, L2, 200, stats);
  bn_fin_k<<<2, 256, 0, stream>>>(stats, bnyg, bnyb, 200, 1.f / (float)L2, scsh);
  pool_f328_k<<<2048, 256, 0, stream>>>(out2q, 200, scsh, 2, 2, Y2f, L3);

  // Z path
  gemm8(stream, cmat8, 352, wc18, 1056, outc1q, 300, 300, L1, 300, 1056);
  hipMemsetAsync(stats, 0, sizeof(float) * 600, stream);
  bn_stats8_k<<<512, 1024, 0, stream>>>(outc1q, L1, 300, stats);
  bn_fin_k<<<2, 256, 0, stream>>>(stats, bncg, bncb, 300, 1.f / (float)L1, scsh);
  pool_q8_k<<<2048, 256, 0, stream>>>(outc1q, 300, scsh, 3, 2, z1q, 320, L2);

  gemm8(stream, z1q, 320, wc28, 320, outc2q, 300, 300, L2, 300, 320);
  hipMemsetAsync(stats, 0, sizeof(float) * 600, stream);
  bn_stats8_k<<<512, 1024, 0, stream>>>(outc2q, L2, 300, stats);
  bn_fin_k<<<2, 256, 0, stream>>>(stats, bncg, bncb, 300, 1.f / (float)L2, scsh);
  pool_f328_k<<<2048, 256, 0, stream>>>(outc2q, 300, scsh, 2, 2, Z2f, L3);

  // ---- final MLP product + mean + sigmoid ----
  hipMemsetAsync(acc2, 0, sizeof(float) * 2, stream);
  final_dot_k<<<256, 256, 0, stream>>>(Y2f, Z2f, mlpyw, mlpyb, mlpzw, mlpzb, acc2, L3);
  final_out_k<<<1, 64, 0, stream>>>(acc2, 1.f / (float)L3, (float*)d_out);
}